// Round 2
// baseline (1548.537 us; speedup 1.0000x reference)
//
#include <hip/hip_runtime.h>
#include <hip/hip_bf16.h>

#define CC 64
#define HW 9216
#define IMG 96

// ---------------- dilated 3x3 conv (pad=2, dil=2) -> y (fp32, natural C,HW layout)
__global__ __launch_bounds__(256) void conv_dil_kernel(
    const float* __restrict__ x,
    const float* __restrict__ dW,
    const float* __restrict__ db,
    float* __restrict__ y)
{
    __shared__ float wsh[CC * 9];
    int b = blockIdx.x;             // 64 co * 36 chunks
    int co = b / 36;
    int m  = (b % 36) * 256 + threadIdx.x;
    for (int i = threadIdx.x; i < CC * 9; i += 256)
        wsh[i] = dW[co * CC * 9 + i];
    __syncthreads();
    int h = m / IMG, w = m % IMG;
    float acc = db[co];
    for (int ci = 0; ci < CC; ++ci) {
        const float* xp = x + ci * HW;
        const float* wp = wsh + ci * 9;
        #pragma unroll
        for (int kh = 0; kh < 3; ++kh) {
            int hh = h + kh * 2 - 2;
            if (hh < 0 || hh >= IMG) continue;
            #pragma unroll
            for (int kw = 0; kw < 3; ++kw) {
                int ww = w + kw * 2 - 2;
                if (ww < 0 || ww >= IMG) continue;
                acc += wp[kh * 3 + kw] * xp[hh * IMG + ww];
            }
        }
    }
    y[co * HW + m] = acc;
}

// ---------------- 1x1 conv -> v (fp32, natural C,HW layout)
__global__ __launch_bounds__(256) void conv1x1_kernel(
    const float* __restrict__ x,
    const float* __restrict__ cW,
    const float* __restrict__ cb,
    float* __restrict__ v)
{
    __shared__ float wsh[CC];
    int b = blockIdx.x;
    int co = b / 36;
    int m  = (b % 36) * 256 + threadIdx.x;
    if (threadIdx.x < CC) wsh[threadIdx.x] = cW[co * CC + threadIdx.x];
    __syncthreads();
    float acc = cb[co];
    for (int ci = 0; ci < CC; ++ci)
        acc += wsh[ci] * x[ci * HW + m];
    v[co * HW + m] = acc;
}

// ---------------- flash-style attention
// Q[n,c] = y_flat[n*64+c]; K[c,m] = y_flat[c*9216+m]; V[m,c] = v_flat[m*64+c]
// out[c*9216+n] = x[c*9216+n] + (softmax(mask(QK))V)[n,c]
__global__ __launch_bounds__(256) void attn_kernel(
    const float* __restrict__ y,
    const float* __restrict__ v,
    const float* __restrict__ x,
    float* __restrict__ out)
{
    __shared__ float Kt[64 * 64];    // Kt[c*64 + m']
    __shared__ float Vt[64 * 64];    // Vt[m'*64 + c]
    __shared__ float qs[16 * 64];    // qs[r*64 + c]
    __shared__ float ps[16 * 64];    // ps[r*64 + m']

    const int t    = threadIdx.x;
    const int lane = t & 63;
    const int wv   = t >> 6;         // 0..3
    const int n0   = blockIdx.x * 16;

    // load Q rows (contiguous chunk of y_flat); each wave writes the rows it reads
    {
        const float4* qsrc = (const float4*)(y + n0 * 64);
        ((float4*)qs)[t] = qsrc[t];
    }

    float mi[4], li[4], acc[4];
    #pragma unroll
    for (int j = 0; j < 4; ++j) { mi[j] = -1e30f; li[j] = 0.f; acc[j] = 0.f; }

    for (int tile = 0; tile < 144; ++tile) {
        const int m0 = tile * 64;
        __syncthreads();             // previous tile fully consumed (also covers qs load)
        // stage K tile: 64 rows of 64 contiguous floats, stride HW
        for (int i = t; i < 1024; i += 256) {
            int c = i >> 4, q4 = i & 15;
            ((float4*)Kt)[i] = *(const float4*)(y + c * HW + m0 + q4 * 4);
        }
        // stage V tile: contiguous 4096 floats
        {
            const float4* vsrc = (const float4*)(v + m0 * 64);
            for (int i = t; i < 1024; i += 256) ((float4*)Vt)[i] = vsrc[i];
        }
        __syncthreads();

        // scores: lane handles m'=lane for this wave's 4 rows
        float s[4] = {0.f, 0.f, 0.f, 0.f};
        for (int c = 0; c < 64; ++c) {
            float kc = Kt[c * 64 + lane];
            #pragma unroll
            for (int j = 0; j < 4; ++j)
                s[j] += qs[(wv * 4 + j) * 64 + c] * kc;
        }
        #pragma unroll
        for (int j = 0; j < 4; ++j)
            s[j] = (fabsf(s[j]) > 0.3f) ? s[j] : 0.f;   // threshold mask (to ZERO)

        // online softmax per row (wave-wide reductions)
        #pragma unroll
        for (int j = 0; j < 4; ++j) {
            float mx = s[j];
            #pragma unroll
            for (int off = 32; off; off >>= 1)
                mx = fmaxf(mx, __shfl_xor(mx, off, 64));
            float mnew = fmaxf(mi[j], mx);
            float p = __expf(s[j] - mnew);
            float sum = p;
            #pragma unroll
            for (int off = 32; off; off >>= 1)
                sum += __shfl_xor(sum, off, 64);
            float alpha = __expf(mi[j] - mnew);
            li[j]  = li[j] * alpha + sum;
            acc[j] *= alpha;
            mi[j]  = mnew;
            ps[(wv * 4 + j) * 64 + lane] = p;
        }

        // PV: lane owns channel c=lane; same-wave LDS RAW is processed in order
        for (int mp = 0; mp < 64; ++mp) {
            float vv = Vt[mp * 64 + lane];
            #pragma unroll
            for (int j = 0; j < 4; ++j)
                acc[j] += ps[(wv * 4 + j) * 64 + mp] * vv;
        }
    }

    // finalize into LDS (reuse Kt), then transpose write + residual
    __syncthreads();
    #pragma unroll
    for (int j = 0; j < 4; ++j)
        Kt[(wv * 4 + j) * 64 + lane] = acc[j] / li[j];
    __syncthreads();

    for (int i = t; i < 1024; i += 256) {
        int c2 = i >> 4;   // 0..63
        int r2 = i & 15;   // 0..15
        int idx = c2 * HW + n0 + r2;
        out[idx] = x[idx] + Kt[r2 * 64 + c2];
    }
}

extern "C" void kernel_launch(void* const* d_in, const int* in_sizes, int n_in,
                              void* d_out, int out_size, void* d_ws, size_t ws_size,
                              hipStream_t stream)
{
    const float* x  = (const float*)d_in[0];
    const float* dW = (const float*)d_in[1];
    const float* db = (const float*)d_in[2];
    const float* cW = (const float*)d_in[3];
    const float* cb = (const float*)d_in[4];
    float* out = (float*)d_out;

    float* y = (float*)d_ws;               // 64*9216 fp32 = 2.36 MB
    float* v = y + CC * HW;                // another 2.36 MB

    conv_dil_kernel<<<dim3(64 * 36), dim3(256), 0, stream>>>(x, dW, db, y);
    conv1x1_kernel<<<dim3(64 * 36), dim3(256), 0, stream>>>(x, cW, cb, v);
    attn_kernel<<<dim3(HW / 16), dim3(256), 0, stream>>>(y, v, x, out);
}

// Round 4
// 244.476 us; speedup vs baseline: 6.3341x; 6.3341x over previous
//
#include <hip/hip_runtime.h>
#include <hip/hip_bf16.h>

#define CC 64
#define HW 9216
#define IMG 96

typedef __attribute__((ext_vector_type(8))) short bfrag8;   // 8 bf16 (4 VGPRs)
typedef __attribute__((ext_vector_type(4))) float f32x4;

// ---------------- dilated 3x3 conv (pad=2, dil=2)
// writes y as hi/lo bf16 pair in BOTH layouts: flat chw (Q rows) and kt[m*64+c] (K^T)
__global__ __launch_bounds__(256) void conv_dil_kernel(
    const float* __restrict__ x, const float* __restrict__ dW, const float* __restrict__ db,
    __hip_bfloat16* __restrict__ y_hi, __hip_bfloat16* __restrict__ y_lo,
    __hip_bfloat16* __restrict__ kt_hi, __hip_bfloat16* __restrict__ kt_lo)
{
    const int b = blockIdx.x;            // 16 co-groups * 36 chunks
    const int cog = b / 36, chunk = b % 36;
    const int t = threadIdx.x;
    const int m = chunk * 256 + t;
    const int h = m / IMG, w = m % IMG;

    int off[9]; float fv[9];
    #pragma unroll
    for (int kh = 0; kh < 3; ++kh)
        #pragma unroll
        for (int kw = 0; kw < 3; ++kw) {
            int hh = h + 2 * kh - 2, ww = w + 2 * kw - 2;
            bool ok = (hh >= 0 && hh < IMG && ww >= 0 && ww < IMG);
            int hc = min(max(hh, 0), IMG - 1), wc = min(max(ww, 0), IMG - 1);
            off[kh * 3 + kw] = hc * IMG + wc;
            fv[kh * 3 + kw] = ok ? 1.f : 0.f;
        }
    const int co = cog * 4;
    float a0 = db[co], a1 = db[co + 1], a2 = db[co + 2], a3 = db[co + 3];
    const float* w0 = dW + (co + 0) * 576;
    const float* w1 = dW + (co + 1) * 576;
    const float* w2 = dW + (co + 2) * 576;
    const float* w3 = dW + (co + 3) * 576;

    for (int ci = 0; ci < CC; ++ci) {
        const float* xp = x + ci * HW;
        float tv[9];
        #pragma unroll
        for (int k = 0; k < 9; ++k) tv[k] = xp[off[k]] * fv[k];
        #pragma unroll
        for (int k = 0; k < 9; ++k) {
            a0 += w0[ci * 9 + k] * tv[k];   // weight idx block-uniform -> s_load
            a1 += w1[ci * 9 + k] * tv[k];
            a2 += w2[ci * 9 + k] * tv[k];
            a3 += w3[ci * 9 + k] * tv[k];
        }
    }
    float accs[4] = {a0, a1, a2, a3};
    #pragma unroll
    for (int cc = 0; cc < 4; ++cc) {
        float av = accs[cc];
        __hip_bfloat16 hv = __float2bfloat16(av);
        __hip_bfloat16 lv = __float2bfloat16(av - __bfloat162float(hv));
        int fidx = (co + cc) * HW + m;      // flat chw = Q layout via reinterpret
        int kidx = m * 64 + (co + cc);      // K^T[m][c]
        y_hi[fidx] = hv;  y_lo[fidx] = lv;
        kt_hi[kidx] = hv; kt_lo[kidx] = lv;
    }
}

// ---------------- 1x1 conv: writes vt[c][m] (transposed V-matrix, bf16)
__global__ __launch_bounds__(256) void conv1x1_kernel(
    const float* __restrict__ x, const float* __restrict__ cW, const float* __restrict__ cb,
    __hip_bfloat16* __restrict__ vt)
{
    const int b = blockIdx.x;
    const int cog = b / 36, chunk = b % 36;
    const int t = threadIdx.x;
    const int m = chunk * 256 + t;
    const int co = cog * 4;
    float a0 = cb[co], a1 = cb[co + 1], a2 = cb[co + 2], a3 = cb[co + 3];
    for (int ci = 0; ci < CC; ++ci) {
        float xv = x[ci * HW + m];
        a0 += cW[(co + 0) * CC + ci] * xv;
        a1 += cW[(co + 1) * CC + ci] * xv;
        a2 += cW[(co + 2) * CC + ci] * xv;
        a3 += cW[(co + 3) * CC + ci] * xv;
    }
    float accs[4] = {a0, a1, a2, a3};
    #pragma unroll
    for (int cc = 0; cc < 4; ++cc) {
        // V[row][col]: flat idx i=(co+cc)*9216+m -> row=i>>6, col=i&63; vt[col][row]
        vt[(m & 63) * HW + (co + cc) * 144 + (m >> 6)] = __float2bfloat16(accs[cc]);
    }
}

// ---------------- MFMA flash attention, BM=64 rows, 4 m-splits, BN=64 per iter
// Split-precision QK: S = qh*kh + qh*kl + ql*kh (effective ~16-bit mantissa)
__global__ __launch_bounds__(256, 2) void attn_kernel(
    const __hip_bfloat16* __restrict__ kt_hi, const __hip_bfloat16* __restrict__ kt_lo,
    const __hip_bfloat16* __restrict__ vt,
    const __hip_bfloat16* __restrict__ y_hi, const __hip_bfloat16* __restrict__ y_lo,
    float* __restrict__ acc_ws, float* __restrict__ m_ws, float* __restrict__ l_ws)
{
    __shared__ __hip_bfloat16 sKTh[64 * 72];       // [m_local][c], stride 72 bf16 (144 B)
    __shared__ __hip_bfloat16 sKTl[64 * 72];
    __shared__ __hip_bfloat16 sVT[64 * 72];        // [c][m_local]
    __shared__ __hip_bfloat16 sPS[4 * 16 * 72];    // per-wave P [row][m_local]

    const int t = threadIdx.x;
    const int L = t & 63, w = t >> 6;
    const int g = L >> 4, c16 = L & 15;
    const int qb = blockIdx.x >> 2, sp = blockIdx.x & 3;
    const int n0 = qb * 64;
    const int mbase = sp * 2304;
    __hip_bfloat16* psw = (__hip_bfloat16*)sPS + w * 16 * 72;

    // Q A-fragments: A[row=L&15][k=g*8+j], rows n0+16w+c16, kept in regs all kernel
    bfrag8 qah[2], qal[2];
    #pragma unroll
    for (int kc = 0; kc < 2; ++kc) {
        qah[kc] = *(const bfrag8*)(y_hi + (n0 + w * 16 + c16) * 64 + g * 8 + kc * 32);
        qal[kc] = *(const bfrag8*)(y_lo + (n0 + w * 16 + c16) * 64 + g * 8 + kc * 32);
    }

    float mi[4], li[4];
    f32x4 acc[4];
    #pragma unroll
    for (int j = 0; j < 4; ++j) { mi[j] = -1e30f; li[j] = 0.f; }
    #pragma unroll
    for (int ct = 0; ct < 4; ++ct) acc[ct] = (f32x4){0.f, 0.f, 0.f, 0.f};

    for (int it = 0; it < 36; ++it) {
        const int m0 = mbase + it * 64;
        __syncthreads();
        // stage K^T hi/lo and V^T tiles (coalesced uint4 -> padded b128 rows)
        {
            int idx = t;
            #pragma unroll
            for (int rep = 0; rep < 2; ++rep, idx += 256) {
                int row = idx >> 3, ch = idx & 7;
                *(uint4*)&sKTh[row * 72 + ch * 8] = *(const uint4*)&kt_hi[(m0 + row) * 64 + ch * 8];
                *(uint4*)&sKTl[row * 72 + ch * 8] = *(const uint4*)&kt_lo[(m0 + row) * 64 + ch * 8];
                *(uint4*)&sVT[row * 72 + ch * 8]  = *(const uint4*)&vt[row * HW + m0 + ch * 8];
            }
        }
        __syncthreads();

        // S = Q K, split precision (4 m-tiles of 16; D: col=c16, rows 4g+j)
        f32x4 s[4];
        #pragma unroll
        for (int mt = 0; mt < 4; ++mt) {
            f32x4 a0 = (f32x4){0.f, 0.f, 0.f, 0.f};
            #pragma unroll
            for (int kc = 0; kc < 2; ++kc) {
                bfrag8 kbh = *(const bfrag8*)&sKTh[(mt * 16 + c16) * 72 + g * 8 + kc * 32];
                bfrag8 kbl = *(const bfrag8*)&sKTl[(mt * 16 + c16) * 72 + g * 8 + kc * 32];
                a0 = __builtin_amdgcn_mfma_f32_16x16x32_bf16(qah[kc], kbh, a0, 0, 0, 0);
                a0 = __builtin_amdgcn_mfma_f32_16x16x32_bf16(qah[kc], kbl, a0, 0, 0, 0);
                a0 = __builtin_amdgcn_mfma_f32_16x16x32_bf16(qal[kc], kbh, a0, 0, 0, 0);
            }
            s[mt] = a0;
        }
        // threshold mask to ZERO
        #pragma unroll
        for (int mt = 0; mt < 4; ++mt)
            #pragma unroll
            for (int j = 0; j < 4; ++j)
                s[mt][j] = (fabsf(s[mt][j]) > 0.3f) ? s[mt][j] : 0.f;

        // online softmax per row (rows 4g+j; 16 cols/lane, shfl across the 16-lane groups)
        #pragma unroll
        for (int j = 0; j < 4; ++j) {
            float mx = fmaxf(fmaxf(s[0][j], s[1][j]), fmaxf(s[2][j], s[3][j]));
            mx = fmaxf(mx, __shfl_xor(mx, 1, 64));
            mx = fmaxf(mx, __shfl_xor(mx, 2, 64));
            mx = fmaxf(mx, __shfl_xor(mx, 4, 64));
            mx = fmaxf(mx, __shfl_xor(mx, 8, 64));
            float mnew = fmaxf(mi[j], mx);
            // round p through bf16 so li matches the P actually used in PV
            __hip_bfloat16 b0 = __float2bfloat16(__expf(s[0][j] - mnew));
            __hip_bfloat16 b1 = __float2bfloat16(__expf(s[1][j] - mnew));
            __hip_bfloat16 b2 = __float2bfloat16(__expf(s[2][j] - mnew));
            __hip_bfloat16 b3 = __float2bfloat16(__expf(s[3][j] - mnew));
            float sum = __bfloat162float(b0) + __bfloat162float(b1) +
                        __bfloat162float(b2) + __bfloat162float(b3);
            sum += __shfl_xor(sum, 1, 64);
            sum += __shfl_xor(sum, 2, 64);
            sum += __shfl_xor(sum, 4, 64);
            sum += __shfl_xor(sum, 8, 64);
            float alpha = __expf(mi[j] - mnew);
            li[j] = li[j] * alpha + sum;
            mi[j] = mnew;
            #pragma unroll
            for (int ct = 0; ct < 4; ++ct) acc[ct][j] *= alpha;
            const int prow = 4 * g + j;
            psw[prow * 72 + 0 * 16 + c16] = b0;
            psw[prow * 72 + 1 * 16 + c16] = b1;
            psw[prow * 72 + 2 * 16 + c16] = b2;
            psw[prow * 72 + 3 * 16 + c16] = b3;
        }

        // PV: A = P (A-layout from psw, same-wave LDS RAW is ordered), B = V^T tile
        bfrag8 pa[2];
        #pragma unroll
        for (int kc = 0; kc < 2; ++kc)
            pa[kc] = *(const bfrag8*)&psw[c16 * 72 + g * 8 + kc * 32];
        #pragma unroll
        for (int ct = 0; ct < 4; ++ct)
            #pragma unroll
            for (int kc = 0; kc < 2; ++kc) {
                bfrag8 vb = *(const bfrag8*)&sVT[(ct * 16 + c16) * 72 + g * 8 + kc * 32];
                acc[ct] = __builtin_amdgcn_mfma_f32_16x16x32_bf16(pa[kc], vb, acc[ct], 0, 0, 0);
            }
    }

    // write partials (no divide; merge kernel combines splits)
    const int base = qb * 4 + sp;
    #pragma unroll
    for (int ct = 0; ct < 4; ++ct)
        #pragma unroll
        for (int j = 0; j < 4; ++j)
            acc_ws[base * 4096 + (w * 16 + 4 * g + j) * 64 + ct * 16 + c16] = acc[ct][j];
    if (c16 == 0) {
        #pragma unroll
        for (int j = 0; j < 4; ++j) {
            m_ws[base * 64 + w * 16 + 4 * g + j] = mi[j];
            l_ws[base * 64 + w * 16 + 4 * g + j] = li[j];
        }
    }
}

// ---------------- merge splits + residual + transpose to (C, HW)
__global__ __launch_bounds__(256) void merge_kernel(
    const float* __restrict__ acc_ws, const float* __restrict__ m_ws, const float* __restrict__ l_ws,
    const float* __restrict__ x, float* __restrict__ out)
{
    __shared__ float wsh[4 * 64];
    __shared__ float att[64 * 65];
    const int qb = blockIdx.x;
    const int t = threadIdx.x;
    if (t < 64) {
        float m0 = m_ws[(qb * 4 + 0) * 64 + t];
        float m1 = m_ws[(qb * 4 + 1) * 64 + t];
        float m2 = m_ws[(qb * 4 + 2) * 64 + t];
        float m3 = m_ws[(qb * 4 + 3) * 64 + t];
        float ms = fmaxf(fmaxf(m0, m1), fmaxf(m2, m3));
        float e0 = __expf(m0 - ms), e1 = __expf(m1 - ms), e2 = __expf(m2 - ms), e3 = __expf(m3 - ms);
        float L = l_ws[(qb * 4 + 0) * 64 + t] * e0 + l_ws[(qb * 4 + 1) * 64 + t] * e1 +
                  l_ws[(qb * 4 + 2) * 64 + t] * e2 + l_ws[(qb * 4 + 3) * 64 + t] * e3;
        float inv = 1.f / L;
        wsh[0 * 64 + t] = e0 * inv;
        wsh[1 * 64 + t] = e1 * inv;
        wsh[2 * 64 + t] = e2 * inv;
        wsh[3 * 64 + t] = e3 * inv;
    }
    __syncthreads();
    for (int i = t; i < 4096; i += 256) {
        int r = i >> 6, c = i & 63;
        float v = 0.f;
        #pragma unroll
        for (int sp = 0; sp < 4; ++sp)
            v += acc_ws[(qb * 4 + sp) * 4096 + r * 64 + c] * wsh[sp * 64 + r];
        att[c * 65 + r] = v;
    }
    __syncthreads();
    const int n0 = qb * 64;
    for (int i = t; i < 4096; i += 256) {
        int c = i >> 6, r = i & 63;
        int idx = c * HW + n0 + r;
        out[idx] = x[idx] + att[c * 65 + r];
    }
}

extern "C" void kernel_launch(void* const* d_in, const int* in_sizes, int n_in,
                              void* d_out, int out_size, void* d_ws, size_t ws_size,
                              hipStream_t stream)
{
    const float* x  = (const float*)d_in[0];
    const float* dW = (const float*)d_in[1];
    const float* db = (const float*)d_in[2];
    const float* cW = (const float*)d_in[3];
    const float* cb = (const float*)d_in[4];
    float* out = (float*)d_out;

    char* ws = (char*)d_ws;
    __hip_bfloat16* y_hi  = (__hip_bfloat16*)(ws);                       // 1,179,648 B
    __hip_bfloat16* y_lo  = (__hip_bfloat16*)(ws + 1179648);             // 1,179,648 B
    __hip_bfloat16* kt_hi = (__hip_bfloat16*)(ws + 2359296);             // 1,179,648 B
    __hip_bfloat16* kt_lo = (__hip_bfloat16*)(ws + 3538944);             // 1,179,648 B
    __hip_bfloat16* vt    = (__hip_bfloat16*)(ws + 4718592);             // 1,179,648 B
    float* acc_ws         = (float*)(ws + 5898240);                      // 9,437,184 B
    float* m_ws           = (float*)(ws + 15335424);                     //   147,456 B
    float* l_ws           = (float*)(ws + 15482880);                     //   147,456 B

    conv_dil_kernel<<<dim3(16 * 36), dim3(256), 0, stream>>>(x, dW, db, y_hi, y_lo, kt_hi, kt_lo);
    conv1x1_kernel<<<dim3(16 * 36), dim3(256), 0, stream>>>(x, cW, cb, vt);
    attn_kernel<<<dim3(576), dim3(256), 0, stream>>>(kt_hi, kt_lo, vt, y_hi, y_lo, acc_ws, m_ws, l_ws);
    merge_kernel<<<dim3(144), dim3(256), 0, stream>>>(acc_ws, m_ws, l_ws, x, out);
}